// Round 8
// baseline (452.322 us; speedup 1.0000x reference)
//
#include <hip/hip_runtime.h>
#include <math.h>

#define N_NODES 50000
#define N_EDGES 1600000
#define D 128
#define BN_EPS 1e-5f

#define NSLICE 8
#define SLICE_NODES 6250        // divides 50000 exactly; src-bucket granularity for gather L2 locality
#define SUBB 24                 // slots per (node, src-slice); Poisson(4), P(>=24)~8e-12
#define ROWL (NSLICE * SUBB)    // 192 u16 per node = 384 B
#define NREP 64                 // BN partial-sum replicas

// R16: LDS-scatter CSR build (WIN: fill wall eliminated). R2/R3/R5 triangulated
// that the old fill wall was the 1.6M returning L2 atomics + dependent 2B
// scatters; phase A bins edges by dst-range (bulk-reserved appends), phase B
// scatters ENTIRELY in LDS and writes csr/cnt8 coalesced.
#define NRANGE 500
#define RANGE_NODES 100         // 500 * 100 = 50000 exact
#define NSUB 8                  // sub-heads per range (blockIdx&7) to cut reserve contention
#define SEG_CAP 512             // per-(range,sub) list segment; mean 400, +5.6 sigma
#define BIN_TILE 2048
#define BIN_CAP2 16             // per-tile per-range LDS bucket; mean 4.1, P(>16)~5e-6
#define BIN_BLOCKS ((N_EDGES + BIN_TILE - 1) / BIN_TILE)  // 782
#define GEMM0_BLOCKS ((N_NODES + 63) / 64)   // 782 (64 rows, 4 waves) — fused with phase A
#define GEMM_BLOCKS ((N_NODES + 31) / 32)    // 1563 (32 rows, 2 waves)

typedef __attribute__((ext_vector_type(8))) short short8;
typedef __attribute__((ext_vector_type(8))) unsigned short ushort8v;
typedef __attribute__((ext_vector_type(4))) float f32x4;

// bf16 helpers (manual, RNE)
__device__ __forceinline__ unsigned short f2bf(float f) {
    unsigned u = __float_as_uint(f);
    u += 0x7FFFu + ((u >> 16) & 1u);
    return (unsigned short)(u >> 16);
}
__device__ __forceinline__ float bf2f(unsigned short u) {
    return __uint_as_float(((unsigned)u) << 16);
}

// ============================================================
// GEMM body (16 rows per wave): out[rowbase..rowbase+15] = act(A) @ W
//   apply_bn=0: A = Af32 (fp32 -> bf16), act = identity
//   apply_bn=1: A = Abf (bf16), act = relu(a*sc+sh)
// Global-direct fragments (m89-verified layouts); optional dinv row-scale.
// ============================================================
__device__ __forceinline__ void gemm_body(int rowbase, const float* __restrict__ Af32,
                                          const unsigned short* __restrict__ Abf,
                                          const unsigned short* __restrict__ Wt,
                                          const float* __restrict__ sc_sh,
                                          const float* __restrict__ dinv,
                                          int apply_bn,
                                          unsigned short* __restrict__ outbf,
                                          unsigned short* Cs) {   // per-wave 16x136 at Cs[w*2176]
    int tid = threadIdx.x;
    int w = tid >> 6;
    int lane = tid & 63;
    int r = lane & 15, quad = lane >> 4;
    rowbase += w * 16;
    int arow = rowbase + r;
    int arowc = (arow < N_NODES) ? arow : 0;

    f32x4 acc[8] = {};
#pragma unroll
    for (int kc = 0; kc < 128; kc += 32) {
        int ko = kc + quad * 8;
        short8 a;
        if (apply_bn) {
            short8 araw = *(const short8*)&Abf[(size_t)arowc * D + ko];
            const float* sc = &sc_sh[ko];
            const float* sh = &sc_sh[128 + ko];
#pragma unroll
            for (int j = 0; j < 8; j++) {
                float v = bf2f((unsigned short)araw[j]);
                v = fmaxf(fmaf(v, sc[j], sh[j]), 0.f);
                a[j] = (short)f2bf(v);
            }
        } else {
            float4 v0 = *(const float4*)&Af32[(size_t)arowc * D + ko];
            float4 v1 = *(const float4*)&Af32[(size_t)arowc * D + ko + 4];
            a[0] = (short)f2bf(v0.x); a[1] = (short)f2bf(v0.y);
            a[2] = (short)f2bf(v0.z); a[3] = (short)f2bf(v0.w);
            a[4] = (short)f2bf(v1.x); a[5] = (short)f2bf(v1.y);
            a[6] = (short)f2bf(v1.z); a[7] = (short)f2bf(v1.w);
        }
#pragma unroll
        for (int ct = 0; ct < 8; ct++) {
            short8 b = *(const short8*)&Wt[(size_t)(ct * 16 + r) * D + ko];
            acc[ct] = __builtin_amdgcn_mfma_f32_16x16x32_bf16(a, b, acc[ct], 0, 0, 0);
        }
    }
    float dv[4] = {1.f, 1.f, 1.f, 1.f};
    if (dinv) {
        float4 d4 = *(const float4*)&dinv[rowbase + quad * 4];  // padded past N
        dv[0] = d4.x; dv[1] = d4.y; dv[2] = d4.z; dv[3] = d4.w;
    }
    // epilogue: wave-private LDS staging (no cross-wave deps -> no barrier)
#pragma unroll
    for (int ct = 0; ct < 8; ct++)
#pragma unroll
        for (int i = 0; i < 4; i++)
            Cs[w * 2176 + (quad * 4 + i) * 136 + ct * 16 + r] = f2bf(acc[ct][i] * dv[i]);

    int r2 = lane >> 2;   // 0..15
    int seg = lane & 3;   // 0..3, 32 cols each
    int orow = rowbase + r2;
    if (orow < N_NODES) {
#pragma unroll
        for (int jj = 0; jj < 4; jj++) {
            *(ushort8v*)&outbf[(size_t)orow * D + seg * 32 + jj * 8] =
                *(const ushort8v*)&Cs[w * 2176 + r2 * 136 + seg * 32 + jj * 8];
        }
    }
}

// ============================================================
// Fused: phase-A edge binning (blocks [0,782)) || layer-0 GEMM ([782,1564)).
// ============================================================
__global__ __launch_bounds__(256) void fused_bin_gemm0_kernel(const int* __restrict__ src,
                                                              const int* __restrict__ dst,
                                                              unsigned int* __restrict__ gcnt,
                                                              unsigned int* __restrict__ glist,
                                                              const float* __restrict__ x,
                                                              const unsigned short* __restrict__ Wt0,
                                                              unsigned short* __restrict__ hwB) {
    __shared__ __align__(16) char smem[34000];   // union: binning 34000B | gemm0 Cs 17408B
    if (blockIdx.x < BIN_BLOCKS) {
        unsigned* lcnt = (unsigned*)smem;                 // [500]
        unsigned* lbuf = (unsigned*)(smem + 2000);        // [500 * 16]
        int tid = threadIdx.x;
        int sub = blockIdx.x & (NSUB - 1);
        for (int i = tid; i < NRANGE; i += 256) lcnt[i] = 0;
        __syncthreads();
        int e0 = blockIdx.x * BIN_TILE;
#pragma unroll
        for (int j = 0; j < BIN_TILE / 256; j++) {
            int e = e0 + j * 256 + tid;
            if (e < N_EDGES) {
                int d = dst[e];
                int s = src[e];
                int rg = d / RANGE_NODES;
                unsigned val = ((unsigned)(d - rg * RANGE_NODES) << 16) | (unsigned)s;
                unsigned pos = atomicAdd(&lcnt[rg], 1u);
                if (pos < BIN_CAP2) {
                    lbuf[rg * BIN_CAP2 + pos] = val;
                } else {   // rare bucket overflow (~10 events/run): direct bounded append
                    unsigned gp = atomicAdd(&gcnt[rg * NSUB + sub], 1u);
                    if (gp < SEG_CAP) glist[(size_t)(rg * NSUB + sub) * SEG_CAP + gp] = val;
                }
            }
        }
        __syncthreads();
        // bulk-reserve + flush: thread t owns ranges t, t+256
        for (int rg = tid; rg < NRANGE; rg += 256) {
            unsigned c = lcnt[rg];
            if (c > BIN_CAP2) c = BIN_CAP2;
            if (c == 0) continue;
            unsigned b = atomicAdd(&gcnt[rg * NSUB + sub], c);
            unsigned base = (unsigned)(rg * NSUB + sub) * SEG_CAP;
            for (unsigned j = 0; j < c; j++) {
                unsigned idx = b + j;
                if (idx < SEG_CAP) glist[base + idx] = lbuf[rg * BIN_CAP2 + j];
            }
        }
    } else {
        gemm_body((blockIdx.x - BIN_BLOCKS) * 64, x, nullptr, Wt0, nullptr, nullptr, 0, hwB,
                  (unsigned short*)smem);
    }
}

// ============================================================
// Phase B: per-range LDS scatter (1.6M LDS atomics, zero global atomics);
// csr + cnt8 written out fully coalesced, exactly once.
// ============================================================
__global__ __launch_bounds__(256) void csr_scatter_kernel(const unsigned int* __restrict__ glist,
                                                          const unsigned int* __restrict__ gcnt,
                                                          unsigned int* __restrict__ cnt8,
                                                          unsigned short* __restrict__ csr) {
    __shared__ __align__(16) unsigned int cnt[RANGE_NODES * 8];        // 3200 B
    __shared__ __align__(16) unsigned short slab[RANGE_NODES * ROWL];  // 38400 B
    int tid = threadIdx.x;
    int rg = blockIdx.x;
    for (int i = tid; i < RANGE_NODES * 8; i += 256) cnt[i] = 0;
    __syncthreads();
#pragma unroll 1
    for (int sub = 0; sub < NSUB; sub++) {
        unsigned c = gcnt[rg * NSUB + sub];
        if (c > SEG_CAP) c = SEG_CAP;
        const unsigned int* seg = glist + (size_t)(rg * NSUB + sub) * SEG_CAP;
        for (unsigned j = tid; j < c; j += 256) {
            unsigned v = seg[j];
            int dl = (int)(v >> 16);
            int s = (int)(v & 0xFFFFu);
            int t = s / SLICE_NODES;
            unsigned pos = atomicAdd(&cnt[dl * 8 + t], 1u);   // LDS atomic
            if (pos < SUBB) slab[dl * ROWL + t * SUBB + pos] = (unsigned short)s;
        }
    }
    __syncthreads();
    // coalesced write-out: 2400 x ushort8 csr + 200 x uint4 counters
    unsigned short* crow = csr + (size_t)rg * RANGE_NODES * ROWL;
    const ushort8v* sl = (const ushort8v*)slab;
    for (int i = tid; i < RANGE_NODES * ROWL / 8; i += 256)
        ((ushort8v*)crow)[i] = sl[i];
    unsigned int* gout = cnt8 + (size_t)rg * RANGE_NODES * 8;
    const uint4* cl = (const uint4*)cnt;
    for (int i = tid; i < RANGE_NODES * 8 / 4; i += 256)
        ((uint4*)gout)[i] = cl[i];
}

// standalone GEMM for layers 1,2 (BN fused, dinv pre-scale); 128 thr = 2 waves,
// 32 rows/block -> 1563 blocks (782-block config wasted a 14/256 dispatch tail)
__global__ __launch_bounds__(128) void gemm_mfma_kernel(const unsigned short* __restrict__ Abf,
                                                        const unsigned short* __restrict__ Wt,
                                                        const float* __restrict__ sc_sh,
                                                        const float* __restrict__ dinv,
                                                        unsigned short* __restrict__ outbf) {
    __shared__ unsigned short Cs[2 * 2176];
    gemm_body(blockIdx.x * 32, nullptr, Abf, Wt, sc_sh, dinv, 1, outbf, Cs);
}

__global__ void compute_dinv_kernel(const unsigned int* __restrict__ cnt8, float* __restrict__ dinv) {
    int n = blockIdx.x * blockDim.x + threadIdx.x;
    if (n < N_NODES) {
        const uint4* c = (const uint4*)&cnt8[n << 3];
        uint4 a = c[0], b = c[1];
        unsigned deg = a.x + a.y + a.z + a.w + b.x + b.y + b.z + b.w;
        dinv[n] = rsqrtf((float)deg + 2.0f);   // improved=True: self-loop weight 2
    }
}

// ============================================================
// Per-layer weight prep: Wt[n][k] = bf16(W[k][n]), 3 layers, 3 blocks.
// ============================================================
__global__ void prep_weights_kernel(const float* __restrict__ W0, const float* __restrict__ W1,
                                    const float* __restrict__ W2, unsigned short* __restrict__ Wt) {
    const float* W = (blockIdx.x == 0) ? W0 : (blockIdx.x == 1) ? W1 : W2;
    unsigned short* o = Wt + (size_t)blockIdx.x * D * D;
    int t = threadIdx.x;
    int n = t & 127, half = t >> 7;
    __attribute__((aligned(16))) unsigned short buf[64];
    for (int j = 0; j < 64; j++) {
        int k = half * 64 + j;
        buf[j] = f2bf(W[(size_t)k * D + n]);
    }
    for (int j = 0; j < 64; j += 8)
        *(ushort8v*)&o[(size_t)n * D + half * 64 + j] = *(const ushort8v*)&buf[j];
}

// ============================================================
// Fused gather + BN-stats — 4 nodes/wave in 16-lane groups, lane owns 8 cols.
// R17: cnt8 hoist + phase-ahead id/weight pipeline (66.6 -> 61.5us).
// R18: j-loop unroll-2 with DUAL accumulators (accE/accO): both hw-row loads
// issue before either FMA block, 2 independent FMA chains -> in-flight loads
// per group 1 -> 2 (kernel is latency-bound: VALUBusy 37%, FETCH structural
// 100MB, VGPR was 32 = compiler allocated zero ILP headroom).
// [16][260] padding kept but demoted: 400K conflict-cycles = ~1% of dispatch.
// Node batching (4 nodes/wave) unchanged (r7/r8 lesson).
//   weighted=1 (layer 0, hw raw):   agg = di*( sum dinv[s]*hw[s] + 2*di*hw[g] )
//   weighted=0 (layers 1+, pre-scaled): agg = di*( sum hw'[s] + 2*hw'[g] )
// ============================================================
#define CNT_AT(t) ((t)==0?ca.x:(t)==1?ca.y:(t)==2?ca.z:(t)==3?ca.w:(t)==4?cb.x:(t)==5?cb.y:(t)==6?cb.z:cb.w)

__global__ __launch_bounds__(256) void gather_agg_stats_kernel(const unsigned short* __restrict__ hw,
                                                               const unsigned short* __restrict__ csr,
                                                               const unsigned int* __restrict__ cnt8,
                                                               const float* __restrict__ dinv,
                                                               unsigned short* __restrict__ out,
                                                               float* __restrict__ rep,
                                                               int weighted) {
    __shared__ float part[16][260];
    int g16 = threadIdx.x >> 4, lane = threadIdx.x & 15;
    int g = blockIdx.x * 16 + g16;             // 3125 * 16 = 50000 exact
    const ushort8v* hwv = (const ushort8v*)hw; // row = 16 x ushort8
    float di = dinv[g];
    ushort8v sv = hwv[(size_t)g * 16 + lane];
    // hoisted counts: 2 vector loads replace 8 serial dependent scalar loads
    uint4 ca = *(const uint4*)&cnt8[g << 3];
    uint4 cb = *(const uint4*)&cnt8[(g << 3) + 4];
    float w0 = weighted ? (2.f * di) : 2.f;
    float accE[8], accO[8];
#pragma unroll
    for (int k = 0; k < 8; k++) { accE[k] = w0 * bf2f((unsigned short)sv[k]); accO[k] = 0.f; }
    const unsigned short* row = csr + (size_t)g * ROWL;

    // pipeline prologue: phase-0 ids/weights
    int sAc = 0, sBc = 0; float wAc = 0.f, wBc = 0.f;
    {
        int dt0 = (int)CNT_AT(0); if (dt0 > SUBB) dt0 = SUBB;
        if (lane < dt0) { sAc = (int)row[lane]; if (weighted) wAc = dinv[sAc]; }
        if (lane + 16 < dt0) { sBc = (int)row[16 + lane]; if (weighted) wBc = dinv[sBc]; }
    }
#pragma unroll
    for (int t = 0; t < NSLICE; t++) {
        int dt = (int)CNT_AT(t); if (dt > SUBB) dt = SUBB;
        // issue phase-(t+1) loads NOW; they complete under phase-t compute
        int sAn = 0, sBn = 0; float wAn = 0.f, wBn = 0.f;
        if (t < NSLICE - 1) {
            int dtn = (int)CNT_AT(t + 1); if (dtn > SUBB) dtn = SUBB;
            if (lane < dtn) { sAn = (int)row[(t + 1) * SUBB + lane]; if (weighted) wAn = dinv[sAn]; }
            if (lane + 16 < dtn) { sBn = (int)row[(t + 1) * SUBB + 16 + lane]; if (weighted) wBn = dinv[sBn]; }
        }
        int d1 = dt < 16 ? dt : 16;
        if (weighted) {
            int j = 0;
            for (; j + 1 < d1; j += 2) {      // unroll-2: 2 loads in flight, 2 acc chains
                int sj0 = __shfl(sAc, j, 16);
                int sj1 = __shfl(sAc, j + 1, 16);
                float wj0 = __shfl(wAc, j, 16);
                float wj1 = __shfl(wAc, j + 1, 16);
                ushort8v v0 = hwv[(size_t)sj0 * 16 + lane];
                ushort8v v1 = hwv[(size_t)sj1 * 16 + lane];
#pragma unroll
                for (int k = 0; k < 8; k++) accE[k] = fmaf(wj0, bf2f((unsigned short)v0[k]), accE[k]);
#pragma unroll
                for (int k = 0; k < 8; k++) accO[k] = fmaf(wj1, bf2f((unsigned short)v1[k]), accO[k]);
            }
            if (j < d1) {
                int sj = __shfl(sAc, j, 16);
                float wj = __shfl(wAc, j, 16);
                ushort8v v = hwv[(size_t)sj * 16 + lane];
#pragma unroll
                for (int k = 0; k < 8; k++) accE[k] = fmaf(wj, bf2f((unsigned short)v[k]), accE[k]);
            }
            for (int jb = 0; jb < dt - 16; jb++) {   // B-half: P~1e-6 per phase
                int sj = __shfl(sBc, jb, 16);
                float wj = __shfl(wBc, jb, 16);
                ushort8v v = hwv[(size_t)sj * 16 + lane];
#pragma unroll
                for (int k = 0; k < 8; k++) accO[k] = fmaf(wj, bf2f((unsigned short)v[k]), accO[k]);
            }
        } else {
            int j = 0;
            for (; j + 1 < d1; j += 2) {
                int sj0 = __shfl(sAc, j, 16);
                int sj1 = __shfl(sAc, j + 1, 16);
                ushort8v v0 = hwv[(size_t)sj0 * 16 + lane];
                ushort8v v1 = hwv[(size_t)sj1 * 16 + lane];
#pragma unroll
                for (int k = 0; k < 8; k++) accE[k] += bf2f((unsigned short)v0[k]);
#pragma unroll
                for (int k = 0; k < 8; k++) accO[k] += bf2f((unsigned short)v1[k]);
            }
            if (j < d1) {
                int sj = __shfl(sAc, j, 16);
                ushort8v v = hwv[(size_t)sj * 16 + lane];
#pragma unroll
                for (int k = 0; k < 8; k++) accE[k] += bf2f((unsigned short)v[k]);
            }
            for (int jb = 0; jb < dt - 16; jb++) {
                int sj = __shfl(sBc, jb, 16);
                ushort8v v = hwv[(size_t)sj * 16 + lane];
#pragma unroll
                for (int k = 0; k < 8; k++) accO[k] += bf2f((unsigned short)v[k]);
            }
        }
        sAc = sAn; sBc = sBn; wAc = wAn; wBc = wBn;
    }
    float acc[8];
    ushort8v o;
#pragma unroll
    for (int k = 0; k < 8; k++) { acc[k] = (accE[k] + accO[k]) * di; o[k] = f2bf(acc[k]); }
    ((ushort8v*)out)[(size_t)g * 16 + lane] = o;

    // BN partials: cols c = lane*8+k; sums at [g16][c], sumsq at [g16][128+c]
    float4 s0 = make_float4(acc[0], acc[1], acc[2], acc[3]);
    float4 s1 = make_float4(acc[4], acc[5], acc[6], acc[7]);
    *(float4*)&part[g16][lane * 8]     = s0;
    *(float4*)&part[g16][lane * 8 + 4] = s1;
    *(float4*)&part[g16][128 + lane * 8] =
        make_float4(s0.x * s0.x, s0.y * s0.y, s0.z * s0.z, s0.w * s0.w);
    *(float4*)&part[g16][128 + lane * 8 + 4] =
        make_float4(s1.x * s1.x, s1.y * s1.y, s1.z * s1.z, s1.w * s1.w);
    __syncthreads();
    int c = threadIdx.x;   // 0..255: 0..127 sums, 128..255 sumsq
    float tot = 0.f;
#pragma unroll
    for (int g2 = 0; g2 < 16; g2++) tot += part[g2][c];
    atomicAdd(&rep[(blockIdx.x & (NREP - 1)) * 256 + c], tot);
}

// ============================================================
// Reduce NREP replicas -> sc/sh; re-zero replicas for next layer.
// ============================================================
__global__ void bn_reduce_finalize_kernel(const float* __restrict__ gamma,
                                          const float* __restrict__ beta,
                                          float* __restrict__ rep,
                                          float* __restrict__ sc_sh) {
    int c = threadIdx.x;
    if (c >= 128) return;
    float s = 0.f, q = 0.f;
#pragma unroll 4
    for (int rr = 0; rr < NREP; rr++) {
        s += rep[rr * 256 + c];
        q += rep[rr * 256 + 128 + c];
        rep[rr * 256 + c] = 0.f;
        rep[rr * 256 + 128 + c] = 0.f;
    }
    float inv_n = 1.0f / (float)N_NODES;
    float mean = s * inv_n;
    float var = q * inv_n - mean * mean;
    float inv = rsqrtf(var + BN_EPS);
    float sc = gamma[c] * inv;
    sc_sh[c] = sc;
    sc_sh[128 + c] = beta[c] - mean * sc;
}

// final layer: bf16 agg -> BN+ReLU -> fp32 d_out
__global__ void bn_apply_kernel(const unsigned short* __restrict__ h,
                                const float* __restrict__ sc_sh,
                                float* __restrict__ out) {
    int i = blockIdx.x * blockDim.x + threadIdx.x;
    int stride = gridDim.x * blockDim.x;
    const int total = N_NODES * 32;
    for (; i < total; i += stride) {
        int cg = i & 31;
        ushort4 u = ((const ushort4*)h)[i];
        float4 sc = ((const float4*)sc_sh)[cg];
        float4 sh = ((const float4*)sc_sh)[32 + cg];
        float4 v;
        v.x = fmaxf(fmaf(bf2f(u.x), sc.x, sh.x), 0.f);
        v.y = fmaxf(fmaf(bf2f(u.y), sc.y, sh.y), 0.f);
        v.z = fmaxf(fmaf(bf2f(u.z), sc.z, sh.z), 0.f);
        v.w = fmaxf(fmaf(bf2f(u.w), sc.w, sh.w), 0.f);
        ((float4*)out)[i] = v;
    }
}

// ============================================================
// Launch
// ============================================================
extern "C" void kernel_launch(void* const* d_in, const int* in_sizes, int n_in,
                              void* d_out, int out_size, void* d_ws, size_t ws_size,
                              hipStream_t stream) {
    const float* x = (const float*)d_in[0];
    const int* ei = (const int*)d_in[1];
    const int* src = ei;
    const int* dst = ei + N_EDGES;
    const float* Wm[3] = {(const float*)d_in[2], (const float*)d_in[6], (const float*)d_in[10]};
    const float* gm[3] = {(const float*)d_in[4], (const float*)d_in[8], (const float*)d_in[12]};
    const float* bm[3] = {(const float*)d_in[5], (const float*)d_in[9], (const float*)d_in[13]};

    char* p = (char*)d_ws;
    auto carve = [&](size_t bytes) { char* r = p; p += (bytes + 255) & ~(size_t)255; return r; };
    unsigned short* hwB    = (unsigned short*)carve((size_t)N_NODES * D * sizeof(unsigned short));
    unsigned short* aggbf  = (unsigned short*)carve((size_t)N_NODES * D * sizeof(unsigned short));
    unsigned short* Wt     = (unsigned short*)carve((size_t)3 * D * D * sizeof(unsigned short));
    float*          dinv   = (float*)carve((N_NODES + 64) * sizeof(float));
    // cnt8 | rep | gcnt contiguous; only rep+gcnt need zeroing (cnt8 is
    // written wholesale by csr_scatter)
    unsigned int*   cnt8   = (unsigned int*)carve((size_t)(N_NODES * 8 + NREP * 256 + NRANGE * NSUB) * sizeof(unsigned int));
    float*          rep    = (float*)(cnt8 + (size_t)N_NODES * 8);
    unsigned int*   gcnt   = cnt8 + (size_t)N_NODES * 8 + NREP * 256;
    unsigned short* csr    = (unsigned short*)carve((size_t)N_NODES * ROWL * sizeof(unsigned short));
    unsigned int*   glist  = (unsigned int*)carve((size_t)NRANGE * NSUB * SEG_CAP * sizeof(unsigned int));
    float*          sc_sh  = (float*)carve(256 * sizeof(float));

    // ---- prep: zero BN replicas + segment heads, transpose weights ----
    hipMemsetAsync(rep, 0, (size_t)(NREP * 256 + NRANGE * NSUB) * sizeof(unsigned int), stream);
    prep_weights_kernel<<<3, 256, 0, stream>>>(Wm[0], Wm[1], Wm[2], Wt);

    // ---- fused: phase-A binning || layer-0 GEMM ----
    fused_bin_gemm0_kernel<<<BIN_BLOCKS + GEMM0_BLOCKS, 256, 0, stream>>>(
        src, dst, gcnt, glist, x, Wt, hwB);

    // ---- phase B: LDS scatter -> csr + cnt8 (atomic-free in global) ----
    csr_scatter_kernel<<<NRANGE, 256, 0, stream>>>(glist, gcnt, cnt8, csr);
    compute_dinv_kernel<<<(N_NODES + 255) / 256, 256, 0, stream>>>(cnt8, dinv);

    // ---- layer 0: weighted gather (hw unscaled) ----
    gather_agg_stats_kernel<<<N_NODES / 16, 256, 0, stream>>>(hwB, csr, cnt8, dinv, aggbf, rep, 1);
    bn_reduce_finalize_kernel<<<1, 128, 0, stream>>>(gm[0], bm[0], rep, sc_sh);

    // ---- layers 1,2: BN fused into GEMM, dinv pre-scaled hw ----
    for (int l = 1; l < 3; l++) {
        gemm_mfma_kernel<<<GEMM_BLOCKS, 128, 0, stream>>>(aggbf, Wt + (size_t)l * D * D, sc_sh, dinv, hwB);
        gather_agg_stats_kernel<<<N_NODES / 16, 256, 0, stream>>>(hwB, csr, cnt8, dinv, aggbf, rep, 0);
        bn_reduce_finalize_kernel<<<1, 128, 0, stream>>>(gm[l], bm[l], rep, sc_sh);
    }
    bn_apply_kernel<<<2048, 256, 0, stream>>>(aggbf, sc_sh, (float*)d_out);
}

// Round 9
// 419.771 us; speedup vs baseline: 1.0775x; 1.0775x over previous
//
#include <hip/hip_runtime.h>
#include <math.h>

#define N_NODES 50000
#define N_EDGES 1600000
#define D 128
#define BN_EPS 1e-5f

#define NSLICE 8
#define SLICE_NODES 6250        // divides 50000 exactly; src-bucket granularity for gather L2 locality
#define SUBB 24                 // slots per (node, src-slice); Poisson(4), P(>=24)~8e-12
#define ROWL (NSLICE * SUBB)    // 192 u16 per node = 384 B
#define NREP 64                 // BN partial-sum replicas

// R16: LDS-scatter CSR build (WIN). R18 dual-acc REVERTED (FETCH +24MB,
// occupancy -16%). R19: gather FETCH = 8 XCD x 12.8MB = compulsory-only ->
// the lever is latency hiding at slice transitions, not miss reduction.
#define NRANGE 500
#define RANGE_NODES 100         // 500 * 100 = 50000 exact
#define NSUB 8                  // sub-heads per range (blockIdx&7) to cut reserve contention
#define SEG_CAP 512             // per-(range,sub) list segment; mean 400, +5.6 sigma
#define BIN_TILE 2048
#define BIN_CAP2 16             // per-tile per-range LDS bucket; mean 4.1, P(>16)~5e-6
#define BIN_BLOCKS ((N_EDGES + BIN_TILE - 1) / BIN_TILE)  // 782
#define GEMM0_BLOCKS ((N_NODES + 63) / 64)   // 782 (64 rows, 4 waves) — fused with phase A
#define GEMM_BLOCKS ((N_NODES + 31) / 32)    // 1563 (32 rows, 2 waves)

typedef __attribute__((ext_vector_type(8))) short short8;
typedef __attribute__((ext_vector_type(8))) unsigned short ushort8v;
typedef __attribute__((ext_vector_type(4))) float f32x4;

// bf16 helpers (manual, RNE)
__device__ __forceinline__ unsigned short f2bf(float f) {
    unsigned u = __float_as_uint(f);
    u += 0x7FFFu + ((u >> 16) & 1u);
    return (unsigned short)(u >> 16);
}
__device__ __forceinline__ float bf2f(unsigned short u) {
    return __uint_as_float(((unsigned)u) << 16);
}

// ============================================================
// GEMM body (16 rows per wave): out[rowbase..rowbase+15] = act(A) @ W
//   apply_bn=0: A = Af32 (fp32 -> bf16), act = identity
//   apply_bn=1: A = Abf (bf16), act = relu(a*sc+sh)
// Global-direct fragments (m89-verified layouts); optional dinv row-scale.
// ============================================================
__device__ __forceinline__ void gemm_body(int rowbase, const float* __restrict__ Af32,
                                          const unsigned short* __restrict__ Abf,
                                          const unsigned short* __restrict__ Wt,
                                          const float* __restrict__ sc_sh,
                                          const float* __restrict__ dinv,
                                          int apply_bn,
                                          unsigned short* __restrict__ outbf,
                                          unsigned short* Cs) {   // per-wave 16x136 at Cs[w*2176]
    int tid = threadIdx.x;
    int w = tid >> 6;
    int lane = tid & 63;
    int r = lane & 15, quad = lane >> 4;
    rowbase += w * 16;
    int arow = rowbase + r;
    int arowc = (arow < N_NODES) ? arow : 0;

    f32x4 acc[8] = {};
#pragma unroll
    for (int kc = 0; kc < 128; kc += 32) {
        int ko = kc + quad * 8;
        short8 a;
        if (apply_bn) {
            short8 araw = *(const short8*)&Abf[(size_t)arowc * D + ko];
            const float* sc = &sc_sh[ko];
            const float* sh = &sc_sh[128 + ko];
#pragma unroll
            for (int j = 0; j < 8; j++) {
                float v = bf2f((unsigned short)araw[j]);
                v = fmaxf(fmaf(v, sc[j], sh[j]), 0.f);
                a[j] = (short)f2bf(v);
            }
        } else {
            float4 v0 = *(const float4*)&Af32[(size_t)arowc * D + ko];
            float4 v1 = *(const float4*)&Af32[(size_t)arowc * D + ko + 4];
            a[0] = (short)f2bf(v0.x); a[1] = (short)f2bf(v0.y);
            a[2] = (short)f2bf(v0.z); a[3] = (short)f2bf(v0.w);
            a[4] = (short)f2bf(v1.x); a[5] = (short)f2bf(v1.y);
            a[6] = (short)f2bf(v1.z); a[7] = (short)f2bf(v1.w);
        }
#pragma unroll
        for (int ct = 0; ct < 8; ct++) {
            short8 b = *(const short8*)&Wt[(size_t)(ct * 16 + r) * D + ko];
            acc[ct] = __builtin_amdgcn_mfma_f32_16x16x32_bf16(a, b, acc[ct], 0, 0, 0);
        }
    }
    float dv[4] = {1.f, 1.f, 1.f, 1.f};
    if (dinv) {
        float4 d4 = *(const float4*)&dinv[rowbase + quad * 4];  // padded past N
        dv[0] = d4.x; dv[1] = d4.y; dv[2] = d4.z; dv[3] = d4.w;
    }
    // epilogue: wave-private LDS staging (no cross-wave deps -> no barrier)
#pragma unroll
    for (int ct = 0; ct < 8; ct++)
#pragma unroll
        for (int i = 0; i < 4; i++)
            Cs[w * 2176 + (quad * 4 + i) * 136 + ct * 16 + r] = f2bf(acc[ct][i] * dv[i]);

    int r2 = lane >> 2;   // 0..15
    int seg = lane & 3;   // 0..3, 32 cols each
    int orow = rowbase + r2;
    if (orow < N_NODES) {
#pragma unroll
        for (int jj = 0; jj < 4; jj++) {
            *(ushort8v*)&outbf[(size_t)orow * D + seg * 32 + jj * 8] =
                *(const ushort8v*)&Cs[w * 2176 + r2 * 136 + seg * 32 + jj * 8];
        }
    }
}

// ============================================================
// Fused: phase-A edge binning (blocks [0,782)) || layer-0 GEMM ([782,1564)).
// ============================================================
__global__ __launch_bounds__(256) void fused_bin_gemm0_kernel(const int* __restrict__ src,
                                                              const int* __restrict__ dst,
                                                              unsigned int* __restrict__ gcnt,
                                                              unsigned int* __restrict__ glist,
                                                              const float* __restrict__ x,
                                                              const unsigned short* __restrict__ Wt0,
                                                              unsigned short* __restrict__ hwB) {
    __shared__ __align__(16) char smem[34000];   // union: binning 34000B | gemm0 Cs 17408B
    if (blockIdx.x < BIN_BLOCKS) {
        unsigned* lcnt = (unsigned*)smem;                 // [500]
        unsigned* lbuf = (unsigned*)(smem + 2000);        // [500 * 16]
        int tid = threadIdx.x;
        int sub = blockIdx.x & (NSUB - 1);
        for (int i = tid; i < NRANGE; i += 256) lcnt[i] = 0;
        __syncthreads();
        int e0 = blockIdx.x * BIN_TILE;
#pragma unroll
        for (int j = 0; j < BIN_TILE / 256; j++) {
            int e = e0 + j * 256 + tid;
            if (e < N_EDGES) {
                int d = dst[e];
                int s = src[e];
                int rg = d / RANGE_NODES;
                unsigned val = ((unsigned)(d - rg * RANGE_NODES) << 16) | (unsigned)s;
                unsigned pos = atomicAdd(&lcnt[rg], 1u);
                if (pos < BIN_CAP2) {
                    lbuf[rg * BIN_CAP2 + pos] = val;
                } else {   // rare bucket overflow (~10 events/run): direct bounded append
                    unsigned gp = atomicAdd(&gcnt[rg * NSUB + sub], 1u);
                    if (gp < SEG_CAP) glist[(size_t)(rg * NSUB + sub) * SEG_CAP + gp] = val;
                }
            }
        }
        __syncthreads();
        // bulk-reserve + flush: thread t owns ranges t, t+256
        for (int rg = tid; rg < NRANGE; rg += 256) {
            unsigned c = lcnt[rg];
            if (c > BIN_CAP2) c = BIN_CAP2;
            if (c == 0) continue;
            unsigned b = atomicAdd(&gcnt[rg * NSUB + sub], c);
            unsigned base = (unsigned)(rg * NSUB + sub) * SEG_CAP;
            for (unsigned j = 0; j < c; j++) {
                unsigned idx = b + j;
                if (idx < SEG_CAP) glist[base + idx] = lbuf[rg * BIN_CAP2 + j];
            }
        }
    } else {
        gemm_body((blockIdx.x - BIN_BLOCKS) * 64, x, nullptr, Wt0, nullptr, nullptr, 0, hwB,
                  (unsigned short*)smem);
    }
}

// ============================================================
// Phase B: per-range LDS scatter (1.6M LDS atomics, zero global atomics);
// csr + cnt8 written out fully coalesced, exactly once.
// R19: dinv folded in (counts already in LDS) — one fewer dispatch.
// ============================================================
__global__ __launch_bounds__(256) void csr_scatter_kernel(const unsigned int* __restrict__ glist,
                                                          const unsigned int* __restrict__ gcnt,
                                                          unsigned int* __restrict__ cnt8,
                                                          unsigned short* __restrict__ csr,
                                                          float* __restrict__ dinv) {
    __shared__ __align__(16) unsigned int cnt[RANGE_NODES * 8];        // 3200 B
    __shared__ __align__(16) unsigned short slab[RANGE_NODES * ROWL];  // 38400 B
    int tid = threadIdx.x;
    int rg = blockIdx.x;
    for (int i = tid; i < RANGE_NODES * 8; i += 256) cnt[i] = 0;
    __syncthreads();
#pragma unroll 1
    for (int sub = 0; sub < NSUB; sub++) {
        unsigned c = gcnt[rg * NSUB + sub];
        if (c > SEG_CAP) c = SEG_CAP;
        const unsigned int* seg = glist + (size_t)(rg * NSUB + sub) * SEG_CAP;
        for (unsigned j = tid; j < c; j += 256) {
            unsigned v = seg[j];
            int dl = (int)(v >> 16);
            int s = (int)(v & 0xFFFFu);
            int t = s / SLICE_NODES;
            unsigned pos = atomicAdd(&cnt[dl * 8 + t], 1u);   // LDS atomic
            if (pos < SUBB) slab[dl * ROWL + t * SUBB + pos] = (unsigned short)s;
        }
    }
    __syncthreads();
    // coalesced write-out: 2400 x ushort8 csr + 200 x uint4 counters
    unsigned short* crow = csr + (size_t)rg * RANGE_NODES * ROWL;
    const ushort8v* sl = (const ushort8v*)slab;
    for (int i = tid; i < RANGE_NODES * ROWL / 8; i += 256)
        ((ushort8v*)crow)[i] = sl[i];
    unsigned int* gout = cnt8 + (size_t)rg * RANGE_NODES * 8;
    const uint4* cl = (const uint4*)cnt;
    for (int i = tid; i < RANGE_NODES * 8 / 4; i += 256)
        ((uint4*)gout)[i] = cl[i];
    // fused dinv: raw degree (pre-clamp), matching old compute_dinv semantics
    for (int i = tid; i < RANGE_NODES; i += 256) {
        unsigned deg = 0;
#pragma unroll
        for (int t = 0; t < 8; t++) deg += cnt[i * 8 + t];
        dinv[rg * RANGE_NODES + i] = rsqrtf((float)deg + 2.0f);   // improved=True: self-loop weight 2
    }
}

// standalone GEMM for layers 1,2 (BN fused, dinv pre-scale); 128 thr = 2 waves,
// 32 rows/block -> 1563 blocks (782-block config wasted a 14/256 dispatch tail)
__global__ __launch_bounds__(128) void gemm_mfma_kernel(const unsigned short* __restrict__ Abf,
                                                        const unsigned short* __restrict__ Wt,
                                                        const float* __restrict__ sc_sh,
                                                        const float* __restrict__ dinv,
                                                        unsigned short* __restrict__ outbf) {
    __shared__ unsigned short Cs[2 * 2176];
    gemm_body(blockIdx.x * 32, nullptr, Abf, Wt, sc_sh, dinv, 1, outbf, Cs);
}

// ============================================================
// Per-layer weight prep: Wt[n][k] = bf16(W[k][n]), 3 layers, 3 blocks.
// ============================================================
__global__ void prep_weights_kernel(const float* __restrict__ W0, const float* __restrict__ W1,
                                    const float* __restrict__ W2, unsigned short* __restrict__ Wt) {
    const float* W = (blockIdx.x == 0) ? W0 : (blockIdx.x == 1) ? W1 : W2;
    unsigned short* o = Wt + (size_t)blockIdx.x * D * D;
    int t = threadIdx.x;
    int n = t & 127, half = t >> 7;
    __attribute__((aligned(16))) unsigned short buf[64];
    for (int j = 0; j < 64; j++) {
        int k = half * 64 + j;
        buf[j] = f2bf(W[(size_t)k * D + n]);
    }
    for (int j = 0; j < 64; j += 8)
        *(ushort8v*)&o[(size_t)n * D + half * 64 + j] = *(const ushort8v*)&buf[j];
}

// ============================================================
// Fused gather + BN-stats — 4 nodes/wave in 16-lane groups, lane owns 8 cols.
// R17: cnt8 hoist + phase-ahead id/weight pipeline (66.6 -> 61.5us).
// R18 dual-acc REVERTED (FETCH +24MB, occupancy -16%, net -4us).
// R19: 2-row VALUE prefetch across phases. FETCH=100MB is compulsory
// (8 XCD x table), stalls cluster at slice transitions (max-of-4-groups,
// ~900cy first-touch). Rows 0,1 of phase t+1 are loaded into pv0/pv1 regs
// at the END of phase t (their ids sAn returned under the j-loop), giving
// them ~600cy head start across the transition. Mean dt=4 -> covers half
// of all gather loads. +8 VGPR only.
//   weighted=1 (layer 0, hw raw):   agg = di*( sum dinv[s]*hw[s] + 2*di*hw[g] )
//   weighted=0 (layers 1+, pre-scaled): agg = di*( sum hw'[s] + 2*hw'[g] )
// ============================================================
#define CNT_AT(t) ((t)==0?ca.x:(t)==1?ca.y:(t)==2?ca.z:(t)==3?ca.w:(t)==4?cb.x:(t)==5?cb.y:(t)==6?cb.z:cb.w)

__global__ __launch_bounds__(256) void gather_agg_stats_kernel(const unsigned short* __restrict__ hw,
                                                               const unsigned short* __restrict__ csr,
                                                               const unsigned int* __restrict__ cnt8,
                                                               const float* __restrict__ dinv,
                                                               unsigned short* __restrict__ out,
                                                               float* __restrict__ rep,
                                                               int weighted) {
    __shared__ float part[16][260];
    int g16 = threadIdx.x >> 4, lane = threadIdx.x & 15;
    int g = blockIdx.x * 16 + g16;             // 3125 * 16 = 50000 exact
    const ushort8v* hwv = (const ushort8v*)hw; // row = 16 x ushort8
    float di = dinv[g];
    ushort8v sv = hwv[(size_t)g * 16 + lane];
    // hoisted counts: 2 vector loads replace 8 serial dependent scalar loads
    uint4 ca = *(const uint4*)&cnt8[g << 3];
    uint4 cb = *(const uint4*)&cnt8[(g << 3) + 4];
    float w0 = weighted ? (2.f * di) : 2.f;
    float acc[8];
#pragma unroll
    for (int k = 0; k < 8; k++) acc[k] = w0 * bf2f((unsigned short)sv[k]);
    const unsigned short* row = csr + (size_t)g * ROWL;

    // pipeline prologue: phase-0 ids/weights, then phase-0 row prefetch
    int sAc = 0, sBc = 0; float wAc = 0.f, wBc = 0.f;
    int dt0;
    {
        dt0 = (int)CNT_AT(0); if (dt0 > SUBB) dt0 = SUBB;
        if (lane < dt0) { sAc = (int)row[lane]; if (weighted) wAc = dinv[sAc]; }
        if (lane + 16 < dt0) { sBc = (int)row[16 + lane]; if (weighted) wBc = dinv[sBc]; }
    }
    ushort8v pv0 = {}, pv1 = {};
    {
        int p0 = __shfl(sAc, 0, 16), p1 = __shfl(sAc, 1, 16);
        if (dt0 > 0) pv0 = hwv[(size_t)p0 * 16 + lane];
        if (dt0 > 1) pv1 = hwv[(size_t)p1 * 16 + lane];
    }
#pragma unroll
    for (int t = 0; t < NSLICE; t++) {
        int dt = (int)CNT_AT(t); if (dt > SUBB) dt = SUBB;
        // issue phase-(t+1) id loads NOW; they complete under phase-t compute
        int sAn = 0, sBn = 0; float wAn = 0.f, wBn = 0.f;
        int dtn = 0;
        if (t < NSLICE - 1) {
            dtn = (int)CNT_AT(t + 1); if (dtn > SUBB) dtn = SUBB;
            if (lane < dtn) { sAn = (int)row[(t + 1) * SUBB + lane]; if (weighted) wAn = dinv[sAn]; }
            if (lane + 16 < dtn) { sBn = (int)row[(t + 1) * SUBB + 16 + lane]; if (weighted) wBn = dinv[sBn]; }
        }
        int d1 = dt < 16 ? dt : 16;
        if (weighted) {
            if (d1 > 0) {
                float wj = __shfl(wAc, 0, 16);
#pragma unroll
                for (int k = 0; k < 8; k++) acc[k] = fmaf(wj, bf2f((unsigned short)pv0[k]), acc[k]);
            }
            if (d1 > 1) {
                float wj = __shfl(wAc, 1, 16);
#pragma unroll
                for (int k = 0; k < 8; k++) acc[k] = fmaf(wj, bf2f((unsigned short)pv1[k]), acc[k]);
            }
            for (int j = 2; j < d1; j++) {
                int sj = __shfl(sAc, j, 16);
                float wj = __shfl(wAc, j, 16);
                ushort8v v = hwv[(size_t)sj * 16 + lane];
#pragma unroll
                for (int k = 0; k < 8; k++) acc[k] = fmaf(wj, bf2f((unsigned short)v[k]), acc[k]);
            }
            for (int jb = 0; jb < dt - 16; jb++) {   // B-half: P~1e-6 per phase
                int sj = __shfl(sBc, jb, 16);
                float wj = __shfl(wBc, jb, 16);
                ushort8v v = hwv[(size_t)sj * 16 + lane];
#pragma unroll
                for (int k = 0; k < 8; k++) acc[k] = fmaf(wj, bf2f((unsigned short)v[k]), acc[k]);
            }
        } else {
            if (d1 > 0) {
#pragma unroll
                for (int k = 0; k < 8; k++) acc[k] += bf2f((unsigned short)pv0[k]);
            }
            if (d1 > 1) {
#pragma unroll
                for (int k = 0; k < 8; k++) acc[k] += bf2f((unsigned short)pv1[k]);
            }
            for (int j = 2; j < d1; j++) {
                int sj = __shfl(sAc, j, 16);
                ushort8v v = hwv[(size_t)sj * 16 + lane];
#pragma unroll
                for (int k = 0; k < 8; k++) acc[k] += bf2f((unsigned short)v[k]);
            }
            for (int jb = 0; jb < dt - 16; jb++) {
                int sj = __shfl(sBc, jb, 16);
                ushort8v v = hwv[(size_t)sj * 16 + lane];
#pragma unroll
                for (int k = 0; k < 8; k++) acc[k] += bf2f((unsigned short)v[k]);
            }
        }
        // issue phase-(t+1) row prefetch (sAn returned under the j-loop above):
        // lands across the slice transition, ahead of consumption
        if (t < NSLICE - 1) {
            int p0 = __shfl(sAn, 0, 16), p1 = __shfl(sAn, 1, 16);
            if (dtn > 0) pv0 = hwv[(size_t)p0 * 16 + lane];
            if (dtn > 1) pv1 = hwv[(size_t)p1 * 16 + lane];
        }
        sAc = sAn; sBc = sBn; wAc = wAn; wBc = wBn;
    }
    ushort8v o;
#pragma unroll
    for (int k = 0; k < 8; k++) { acc[k] *= di; o[k] = f2bf(acc[k]); }
    ((ushort8v*)out)[(size_t)g * 16 + lane] = o;

    // BN partials: cols c = lane*8+k; sums at [g16][c], sumsq at [g16][128+c]
    float4 s0 = make_float4(acc[0], acc[1], acc[2], acc[3]);
    float4 s1 = make_float4(acc[4], acc[5], acc[6], acc[7]);
    *(float4*)&part[g16][lane * 8]     = s0;
    *(float4*)&part[g16][lane * 8 + 4] = s1;
    *(float4*)&part[g16][128 + lane * 8] =
        make_float4(s0.x * s0.x, s0.y * s0.y, s0.z * s0.z, s0.w * s0.w);
    *(float4*)&part[g16][128 + lane * 8 + 4] =
        make_float4(s1.x * s1.x, s1.y * s1.y, s1.z * s1.z, s1.w * s1.w);
    __syncthreads();
    int c = threadIdx.x;   // 0..255: 0..127 sums, 128..255 sumsq
    float tot = 0.f;
#pragma unroll
    for (int g2 = 0; g2 < 16; g2++) tot += part[g2][c];
    atomicAdd(&rep[(blockIdx.x & (NREP - 1)) * 256 + c], tot);
}

// ============================================================
// Reduce NREP replicas -> sc/sh; re-zero replicas for next layer.
// ============================================================
__global__ void bn_reduce_finalize_kernel(const float* __restrict__ gamma,
                                          const float* __restrict__ beta,
                                          float* __restrict__ rep,
                                          float* __restrict__ sc_sh) {
    int c = threadIdx.x;
    if (c >= 128) return;
    float s = 0.f, q = 0.f;
#pragma unroll 4
    for (int rr = 0; rr < NREP; rr++) {
        s += rep[rr * 256 + c];
        q += rep[rr * 256 + 128 + c];
        rep[rr * 256 + c] = 0.f;
        rep[rr * 256 + 128 + c] = 0.f;
    }
    float inv_n = 1.0f / (float)N_NODES;
    float mean = s * inv_n;
    float var = q * inv_n - mean * mean;
    float inv = rsqrtf(var + BN_EPS);
    float sc = gamma[c] * inv;
    sc_sh[c] = sc;
    sc_sh[128 + c] = beta[c] - mean * sc;
}

// final layer: bf16 agg -> BN+ReLU -> fp32 d_out
__global__ void bn_apply_kernel(const unsigned short* __restrict__ h,
                                const float* __restrict__ sc_sh,
                                float* __restrict__ out) {
    int i = blockIdx.x * blockDim.x + threadIdx.x;
    int stride = gridDim.x * blockDim.x;
    const int total = N_NODES * 32;
    for (; i < total; i += stride) {
        int cg = i & 31;
        ushort4 u = ((const ushort4*)h)[i];
        float4 sc = ((const float4*)sc_sh)[cg];
        float4 sh = ((const float4*)sc_sh)[32 + cg];
        float4 v;
        v.x = fmaxf(fmaf(bf2f(u.x), sc.x, sh.x), 0.f);
        v.y = fmaxf(fmaf(bf2f(u.y), sc.y, sh.y), 0.f);
        v.z = fmaxf(fmaf(bf2f(u.z), sc.z, sh.z), 0.f);
        v.w = fmaxf(fmaf(bf2f(u.w), sc.w, sh.w), 0.f);
        ((float4*)out)[i] = v;
    }
}

// ============================================================
// Launch
// ============================================================
extern "C" void kernel_launch(void* const* d_in, const int* in_sizes, int n_in,
                              void* d_out, int out_size, void* d_ws, size_t ws_size,
                              hipStream_t stream) {
    const float* x = (const float*)d_in[0];
    const int* ei = (const int*)d_in[1];
    const int* src = ei;
    const int* dst = ei + N_EDGES;
    const float* Wm[3] = {(const float*)d_in[2], (const float*)d_in[6], (const float*)d_in[10]};
    const float* gm[3] = {(const float*)d_in[4], (const float*)d_in[8], (const float*)d_in[12]};
    const float* bm[3] = {(const float*)d_in[5], (const float*)d_in[9], (const float*)d_in[13]};

    char* p = (char*)d_ws;
    auto carve = [&](size_t bytes) { char* r = p; p += (bytes + 255) & ~(size_t)255; return r; };
    unsigned short* hwB    = (unsigned short*)carve((size_t)N_NODES * D * sizeof(unsigned short));
    unsigned short* aggbf  = (unsigned short*)carve((size_t)N_NODES * D * sizeof(unsigned short));
    unsigned short* Wt     = (unsigned short*)carve((size_t)3 * D * D * sizeof(unsigned short));
    float*          dinv   = (float*)carve((N_NODES + 64) * sizeof(float));
    // cnt8 | rep | gcnt contiguous; only rep+gcnt need zeroing (cnt8 is
    // written wholesale by csr_scatter)
    unsigned int*   cnt8   = (unsigned int*)carve((size_t)(N_NODES * 8 + NREP * 256 + NRANGE * NSUB) * sizeof(unsigned int));
    float*          rep    = (float*)(cnt8 + (size_t)N_NODES * 8);
    unsigned int*   gcnt   = cnt8 + (size_t)N_NODES * 8 + NREP * 256;
    unsigned short* csr    = (unsigned short*)carve((size_t)N_NODES * ROWL * sizeof(unsigned short));
    unsigned int*   glist  = (unsigned int*)carve((size_t)NRANGE * NSUB * SEG_CAP * sizeof(unsigned int));
    float*          sc_sh  = (float*)carve(256 * sizeof(float));

    // ---- prep: zero BN replicas + segment heads, transpose weights ----
    hipMemsetAsync(rep, 0, (size_t)(NREP * 256 + NRANGE * NSUB) * sizeof(unsigned int), stream);
    prep_weights_kernel<<<3, 256, 0, stream>>>(Wm[0], Wm[1], Wm[2], Wt);

    // ---- fused: phase-A binning || layer-0 GEMM ----
    fused_bin_gemm0_kernel<<<BIN_BLOCKS + GEMM0_BLOCKS, 256, 0, stream>>>(
        src, dst, gcnt, glist, x, Wt, hwB);

    // ---- phase B: LDS scatter -> csr + cnt8 + dinv (atomic-free in global) ----
    csr_scatter_kernel<<<NRANGE, 256, 0, stream>>>(glist, gcnt, cnt8, csr, dinv);

    // ---- layer 0: weighted gather (hw unscaled) ----
    gather_agg_stats_kernel<<<N_NODES / 16, 256, 0, stream>>>(hwB, csr, cnt8, dinv, aggbf, rep, 1);
    bn_reduce_finalize_kernel<<<1, 128, 0, stream>>>(gm[0], bm[0], rep, sc_sh);

    // ---- layers 1,2: BN fused into GEMM, dinv pre-scaled hw ----
    for (int l = 1; l < 3; l++) {
        gemm_mfma_kernel<<<GEMM_BLOCKS, 128, 0, stream>>>(aggbf, Wt + (size_t)l * D * D, sc_sh, dinv, hwB);
        gather_agg_stats_kernel<<<N_NODES / 16, 256, 0, stream>>>(hwB, csr, cnt8, dinv, aggbf, rep, 0);
        bn_reduce_finalize_kernel<<<1, 128, 0, stream>>>(gm[l], bm[l], rep, sc_sh);
    }
    bn_apply_kernel<<<2048, 256, 0, stream>>>(aggbf, sc_sh, (float*)d_out);
}